// Round 8
// baseline (761.312 us; speedup 1.0000x reference)
//
#include <hip/hip_runtime.h>
#include <math.h>

// ---------------------------------------------------------------------------
// DAHead: B=8, Cin=512, Ci=128, H=W=64, N=4096, Ck=16, NC=19.
// R13: conv W fragments moved from per-lane global loads (L1-port-bound:
//   all of R8/R9/R10 saturate ~30-36 B/cyc/CU combined port traffic, W
//   dominated, redundant across waves) into LDS, DMA'd once per block per
//   chunk via global_load_lds width=16 (wpack layout is already linear:
//   1KB segment = 1 wave-instr). 2 barriers/chunk: B1 {XL,WL ready} ->
//   X-reg prefetch -> compute (ds_read_b128 W+X, conflict-free) -> B2
//   {WL consumed} -> DMA W[ch+1] + stage X[nb]. Bit-identical math.
//   LDS: merged 80.6KB (2 blk/CU), hilo 62.2KB (2), plain 31.1KB (5).
// Everything else = R12 (730us): pam_attn n0=64, triangle Gram, etc.
// ---------------------------------------------------------------------------

typedef __attribute__((ext_vector_type(8)))  short short8;
typedef __attribute__((ext_vector_type(16))) float f32x16;

#define GLD_LDS16(gp, lp) __builtin_amdgcn_global_load_lds( \
    (const __attribute__((address_space(1))) void*)(gp),    \
    (__attribute__((address_space(3))) void*)(lp), 16, 0, 0)

__device__ inline unsigned short f2bf(float f) {
    union { float f; unsigned u; } v; v.f = f;
    unsigned r = v.u + 0x7fffu + ((v.u >> 16) & 1u);   // RNE
    return (unsigned short)(r >> 16);
}
__device__ inline float bf2f(unsigned short h) {
    union { unsigned u; float f; } v; v.u = ((unsigned)h) << 16;
    return v.f;
}

// ---- weight prepack: W[co][cin][9] fp32 ->
//      wpack[chunk][tap][g(=ci>>3)][co128][ci8]  (bf16) ----------------------
__global__ __launch_bounds__(256) void wpack_kernel(
    const float* __restrict__ W, unsigned short* __restrict__ wp, int Cin, int total)
{
    int idx = blockIdx.x * 256 + threadIdx.x;
    if (idx >= total) return;
    int chunk = idx / 18432;
    int rem   = idx - chunk * 18432;
    int tap   = rem >> 11;
    int rem2  = rem & 2047;
    int g     = rem2 >> 10;
    int co    = (rem2 >> 3) & 127;
    int ci8   = rem2 & 7;
    int cin   = (chunk << 4) + (g << 3) + ci8;
    wp[idx] = f2bf(W[((size_t)co * Cin + cin) * 9 + tap]);
}

__global__ __launch_bounds__(256) void wpack_split_kernel(
    const float* __restrict__ W, unsigned short* __restrict__ wph,
    unsigned short* __restrict__ wpl, int Cin, int total)
{
    int idx = blockIdx.x * 256 + threadIdx.x;
    if (idx >= total) return;
    int chunk = idx / 18432;
    int rem   = idx - chunk * 18432;
    int tap   = rem >> 11;
    int rem2  = rem & 2047;
    int g     = rem2 >> 10;
    int co    = (rem2 >> 3) & 127;
    int ci8   = rem2 & 7;
    int cin   = (chunk << 4) + (g << 3) + ci8;
    float w = W[((size_t)co * Cin + cin) * 9 + tap];
    unsigned short hi = f2bf(w);
    wph[idx] = hi;
    wpl[idx] = f2bf(w - bf2f(hi));
}

// ---- FUSED conv1: plain (Wp1 -> bufA) + hilo (Wc1 -> bufB,bh,bl) ----------
// 256 thr / 4 waves; 1 output row/block; grid (64, 2, 8).
// W in LDS (55,296B) + X dbuf (25,344B) = 80,640B -> 2 blocks/CU.
__global__ __launch_bounds__(256, 2) void conv3x3_merged(
    const float* __restrict__ xin,
    const unsigned short* __restrict__ wpp,
    const unsigned short* __restrict__ wph, const unsigned short* __restrict__ wpl,
    const float* __restrict__ bnp, const float* __restrict__ bnc,
    float* __restrict__ outP, float* __restrict__ outC,
    unsigned short* __restrict__ outh, unsigned short* __restrict__ outl)
{
    const int t   = threadIdx.x;
    const int w2  = t >> 6;
    const int xh  = w2 & 1;
    const int wy  = w2 >> 1;
    const int ln  = t & 63;
    const int l31 = ln & 31;
    const int g   = ln >> 5;
    const int y   = blockIdx.x;
    const int co0 = blockIdx.y << 6;
    const int b   = blockIdx.z;

    const int sr   = t >> 6;
    const int sx   = t & 63;
    const int sgy  = y - 1 + sr;
    const bool sv  = (t < 192) && ((unsigned)sgy < 64u);
    const int spid = sr * 66 + sx + 1;

    __shared__ __align__(16) unsigned short Xh[2][3168];
    __shared__ __align__(16) unsigned short Xo[2][3168];   // 25,344 B
    __shared__ __align__(16) unsigned short WL[27648];     // 55,296 B [arr][tap*2+g][co64][8]

    for (int i = t; i < 792; i += 256) {
        uint4 z; z.x = 0; z.y = 0; z.z = 0; z.w = 0;
        ((uint4*)Xh)[i] = z;
        ((uint4*)Xo)[i] = z;
    }

    const float* xsrc = xin + ((size_t)b << 21) + (sgy << 6) + sx;
    const int co8  = (((wy << 5) + l31) << 3);   // u16 offset of this lane's co in a 512-seg
    const int lnw  = ln << 3;                    // lane u16 offset within a segment

    // W stage: 54 segments of 1KB (3 arrays x 9 taps x 2 g), one gld_lds each
    const int cbase = co0 << 3;

    const f32x16 zero = {0,0,0,0,0,0,0,0,0,0,0,0,0,0,0,0};
    f32x16 ap = zero, ac = zero;

    float xv[16];
    if (sv) {
#pragma unroll
        for (int c = 0; c < 16; c++) xv[c] = xsrc[(size_t)c << 12];
    }
    // stage W chunk 0
    for (int s = w2; s < 54; s += 4) {
        const int arr = s / 18;
        const int sub = s - arr * 18;
        const unsigned short* src = (arr == 0) ? wpp : ((arr == 1) ? wph : wpl);
        GLD_LDS16(src + sub * 1024 + cbase + lnw,
                  (uint4*)(WL + arr * 9216 + sub * 512));
    }
    __syncthreads();   // zero-init + W0 visible

    if (sv) {
        unsigned short th[16], tl[16];
#pragma unroll
        for (int c = 0; c < 16; c++) {
            unsigned short hi = f2bf(xv[c]);
            th[c] = hi; tl[c] = f2bf(xv[c] - bf2f(hi));
        }
        *(uint4*)&Xh[0][spid << 3]          = ((uint4*)th)[0];
        *(uint4*)&Xh[0][1584 + (spid << 3)] = ((uint4*)th)[1];
        *(uint4*)&Xo[0][spid << 3]          = ((uint4*)tl)[0];
        *(uint4*)&Xo[0][1584 + (spid << 3)] = ((uint4*)tl)[1];
    }

    int cur = 0;
    for (int ch = 0; ch < 32; ++ch) {
        __syncthreads();                       // B1: XL[cur] + WL(ch) ready
        const bool pf = (ch < 31);
        if (pf && sv) {
#pragma unroll
            for (int c = 0; c < 16; c++)
                xv[c] = xsrc[((size_t)(ch + 1) << 16) + ((size_t)c << 12)];
        }
#pragma unroll 3
        for (int tap = 0; tap < 9; ++tap) {
            const int dy = tap / 3, dx = tap - dy * 3;
            const int xi = (g ? 1584 : 0) + (((dy * 66) + (xh << 5) + l31 + dx) << 3);
            const int wb = ((tap << 1) + g) * 512 + co8;
            short8 vap = *(const short8*)&WL[wb];
            short8 vah = *(const short8*)&WL[9216 + wb];
            short8 val = *(const short8*)&WL[18432 + wb];
            short8 bh_ = *(const short8*)&Xh[cur][xi];
            short8 bl_ = *(const short8*)&Xo[cur][xi];
            ap = __builtin_amdgcn_mfma_f32_32x32x16_bf16(vap, bh_, ap, 0, 0, 0);
            ac = __builtin_amdgcn_mfma_f32_32x32x16_bf16(vah, bh_, ac, 0, 0, 0);
            ac = __builtin_amdgcn_mfma_f32_32x32x16_bf16(vah, bl_, ac, 0, 0, 0);
            ac = __builtin_amdgcn_mfma_f32_32x32x16_bf16(val, bh_, ac, 0, 0, 0);
        }
        __syncthreads();                       // B2: WL consumed
        if (pf) {
            const size_t wo = (size_t)(ch + 1) * 18432;
            for (int s = w2; s < 54; s += 4) {
                const int arr = s / 18;
                const int sub = s - arr * 18;
                const unsigned short* src = (arr == 0) ? wpp : ((arr == 1) ? wph : wpl);
                GLD_LDS16(src + wo + sub * 1024 + cbase + lnw,
                          (uint4*)(WL + arr * 9216 + sub * 512));
            }
        }
        if (pf && sv) {
            unsigned short th[16], tl[16];
#pragma unroll
            for (int c = 0; c < 16; c++) {
                unsigned short hi = f2bf(xv[c]);
                th[c] = hi; tl[c] = f2bf(xv[c] - bf2f(hi));
            }
            const int nb = cur ^ 1;
            *(uint4*)&Xh[nb][spid << 3]          = ((uint4*)th)[0];
            *(uint4*)&Xh[nb][1584 + (spid << 3)] = ((uint4*)th)[1];
            *(uint4*)&Xo[nb][spid << 3]          = ((uint4*)tl)[0];
            *(uint4*)&Xo[nb][1584 + (spid << 3)] = ((uint4*)tl)[1];
        }
        cur ^= 1;
    }

    const int x = (xh << 5) + l31;
#pragma unroll
    for (int r = 0; r < 16; r++) {
        int c2 = co0 + (wy << 5) + (r & 3) + ((r >> 2) << 3) + (g << 2);
        size_t o = (((size_t)b * 128 + c2) << 12) + (y << 6) + x;
        float vp = fmaf(ap[r], bnp[c2], bnp[128 + c2]);
        vp = vp > 0.f ? vp : 0.f;
        outP[o] = vp;
        float vc = fmaf(ac[r], bnc[c2], bnc[128 + c2]);
        vc = vc > 0.f ? vc : 0.f;
        outC[o] = vc;
        unsigned short hi = f2bf(vc);
        outh[o] = hi;
        outl[o] = f2bf(vc - bf2f(hi));
    }
}

// ---- plain 3x3 conv, bf16 input (conv2p). W-LDS. grid (64,2,8) ------------
// LDS: X 12,672 + W 18,432 = 31,104 B -> 5 blocks/CU.
__global__ __launch_bounds__(256, 5) void conv3x3_bf(
    const unsigned short* __restrict__ xin, int Cin,
    const unsigned short* __restrict__ wpk, const float* __restrict__ bn,
    float* __restrict__ out_f32)
{
    const int t   = threadIdx.x;
    const int w2  = t >> 6;
    const int xh  = w2 & 1;
    const int wy  = w2 >> 1;
    const int ln  = t & 63;
    const int l31 = ln & 31;
    const int g   = ln >> 5;
    const int y   = blockIdx.x;
    const int co0 = blockIdx.y << 6;
    const int b   = blockIdx.z;

    const int sr   = t >> 6;
    const int sx   = t & 63;
    const int sgy  = y - 1 + sr;
    const bool sv  = (t < 192) && ((unsigned)sgy < 64u);
    const int spid = sr * 66 + sx + 1;

    __shared__ __align__(16) unsigned short Xl[2][3168];   // 12,672 B
    __shared__ __align__(16) unsigned short WL[9216];      // 18,432 B

    for (int i = t; i < 792; i += 256) {
        uint4 z; z.x = 0; z.y = 0; z.z = 0; z.w = 0;
        ((uint4*)Xl)[i] = z;
    }

    const unsigned short* xsrc = xin + (((size_t)b * Cin) << 12) + (sgy << 6) + sx;
    const int co8  = (((wy << 5) + l31) << 3);
    const int lnw  = ln << 3;
    const int cbase = co0 << 3;

    const f32x16 zero = {0,0,0,0,0,0,0,0,0,0,0,0,0,0,0,0};
    f32x16 acc = zero;

    unsigned short xv[16];
    if (sv) {
#pragma unroll
        for (int c = 0; c < 16; c++) xv[c] = xsrc[(size_t)c << 12];
    }
    for (int s = w2; s < 18; s += 4)
        GLD_LDS16(wpk + s * 1024 + cbase + lnw, (uint4*)(WL + s * 512));
    __syncthreads();

    if (sv) {
        *(uint4*)&Xl[0][spid << 3]          = ((uint4*)xv)[0];
        *(uint4*)&Xl[0][1584 + (spid << 3)] = ((uint4*)xv)[1];
    }

    const int nchunks = Cin >> 4;
    int cur = 0;
    for (int ch = 0; ch < nchunks; ++ch) {
        __syncthreads();                       // B1
        const bool pf = (ch < nchunks - 1);
        if (pf && sv) {
#pragma unroll
            for (int c = 0; c < 16; c++)
                xv[c] = xsrc[((size_t)(ch + 1) << 16) + ((size_t)c << 12)];
        }
#pragma unroll 3
        for (int tap = 0; tap < 9; ++tap) {
            const int dy = tap / 3, dx = tap - dy * 3;
            const int xi = (g ? 1584 : 0) + (((dy * 66) + (xh << 5) + l31 + dx) << 3);
            short8 a  = *(const short8*)&WL[((tap << 1) + g) * 512 + co8];
            short8 b0 = *(const short8*)&Xl[cur][xi];
            acc = __builtin_amdgcn_mfma_f32_32x32x16_bf16(a, b0, acc, 0, 0, 0);
        }
        __syncthreads();                       // B2
        if (pf) {
            const size_t wo = (size_t)(ch + 1) * 18432;
            for (int s = w2; s < 18; s += 4)
                GLD_LDS16(wpk + wo + s * 1024 + cbase + lnw, (uint4*)(WL + s * 512));
        }
        if (pf && sv) {
            const int nb = cur ^ 1;
            *(uint4*)&Xl[nb][spid << 3]          = ((uint4*)xv)[0];
            *(uint4*)&Xl[nb][1584 + (spid << 3)] = ((uint4*)xv)[1];
        }
        cur ^= 1;
    }

    const int x = (xh << 5) + l31;
#pragma unroll
    for (int r = 0; r < 16; r++) {
        int c2 = co0 + (wy << 5) + (r & 3) + ((r >> 2) << 3) + (g << 2);
        float v = fmaf(acc[r], bn[c2], bn[128 + c2]);
        v = v > 0.f ? v : 0.f;
        out_f32[(((size_t)b * 128 + c2) << 12) + (y << 6) + x] = v;
    }
}

// ---- hilo 3x3 conv, pre-split bf16 inputs (conv2c). W-LDS. grid (64,2,8) --
// LDS: X 25,344 + W 36,864 = 62,208 B -> 2 blocks/CU.
__global__ __launch_bounds__(256, 2) void conv3x3_hilo_bf(
    const unsigned short* __restrict__ xhg, const unsigned short* __restrict__ xlg,
    int Cin, const unsigned short* __restrict__ wph, const unsigned short* __restrict__ wpl,
    const float* __restrict__ bn, float* __restrict__ out_f32)
{
    const int t   = threadIdx.x;
    const int w2  = t >> 6;
    const int xh  = w2 & 1;
    const int wy  = w2 >> 1;
    const int ln  = t & 63;
    const int l31 = ln & 31;
    const int g   = ln >> 5;
    const int y   = blockIdx.x;
    const int co0 = blockIdx.y << 6;
    const int b   = blockIdx.z;

    const int sr   = t >> 6;
    const int sx   = t & 63;
    const int sgy  = y - 1 + sr;
    const bool sv  = (t < 192) && ((unsigned)sgy < 64u);
    const int spid = sr * 66 + sx + 1;

    __shared__ __align__(16) unsigned short Xa[2][3168];
    __shared__ __align__(16) unsigned short Xb[2][3168];   // 25,344 B
    __shared__ __align__(16) unsigned short WL[18432];     // 36,864 B

    for (int i = t; i < 792; i += 256) {
        uint4 z; z.x = 0; z.y = 0; z.z = 0; z.w = 0;
        ((uint4*)Xa)[i] = z;
        ((uint4*)Xb)[i] = z;
    }

    const unsigned short* hsrc = xhg + (((size_t)b * Cin) << 12) + (sgy << 6) + sx;
    const unsigned short* lsrc = xlg + (((size_t)b * Cin) << 12) + (sgy << 6) + sx;
    const int co8  = (((wy << 5) + l31) << 3);
    const int lnw  = ln << 3;
    const int cbase = co0 << 3;

    const f32x16 zero = {0,0,0,0,0,0,0,0,0,0,0,0,0,0,0,0};
    f32x16 acc = zero;

    unsigned short hv[16], lv[16];
    if (sv) {
#pragma unroll
        for (int c = 0; c < 16; c++) { hv[c] = hsrc[(size_t)c << 12]; lv[c] = lsrc[(size_t)c << 12]; }
    }
    for (int s = w2; s < 36; s += 4) {
        const int arr = s / 18;
        const int sub = s - arr * 18;
        const unsigned short* src = arr ? wpl : wph;
        GLD_LDS16(src + sub * 1024 + cbase + lnw, (uint4*)(WL + arr * 9216 + sub * 512));
    }
    __syncthreads();

    if (sv) {
        *(uint4*)&Xa[0][spid << 3]          = ((uint4*)hv)[0];
        *(uint4*)&Xa[0][1584 + (spid << 3)] = ((uint4*)hv)[1];
        *(uint4*)&Xb[0][spid << 3]          = ((uint4*)lv)[0];
        *(uint4*)&Xb[0][1584 + (spid << 3)] = ((uint4*)lv)[1];
    }

    const int nchunks = Cin >> 4;
    int cur = 0;
    for (int ch = 0; ch < nchunks; ++ch) {
        __syncthreads();                       // B1
        const bool pf = (ch < nchunks - 1);
        if (pf && sv) {
#pragma unroll
            for (int c = 0; c < 16; c++) {
                hv[c] = hsrc[((size_t)(ch + 1) << 16) + ((size_t)c << 12)];
                lv[c] = lsrc[((size_t)(ch + 1) << 16) + ((size_t)c << 12)];
            }
        }
#pragma unroll 3
        for (int tap = 0; tap < 9; ++tap) {
            const int dy = tap / 3, dx = tap - dy * 3;
            const int xi = (g ? 1584 : 0) + (((dy * 66) + (xh << 5) + l31 + dx) << 3);
            const int wb = ((tap << 1) + g) * 512 + co8;
            short8 ah  = *(const short8*)&WL[wb];
            short8 al  = *(const short8*)&WL[9216 + wb];
            short8 bh_ = *(const short8*)&Xa[cur][xi];
            short8 bl_ = *(const short8*)&Xb[cur][xi];
            acc = __builtin_amdgcn_mfma_f32_32x32x16_bf16(ah, bh_, acc, 0, 0, 0);
            acc = __builtin_amdgcn_mfma_f32_32x32x16_bf16(ah, bl_, acc, 0, 0, 0);
            acc = __builtin_amdgcn_mfma_f32_32x32x16_bf16(al, bh_, acc, 0, 0, 0);
        }
        __syncthreads();                       // B2
        if (pf) {
            const size_t wo = (size_t)(ch + 1) * 18432;
            for (int s = w2; s < 36; s += 4) {
                const int arr = s / 18;
                const int sub = s - arr * 18;
                const unsigned short* src = arr ? wpl : wph;
                GLD_LDS16(src + wo + sub * 1024 + cbase + lnw,
                          (uint4*)(WL + arr * 9216 + sub * 512));
            }
        }
        if (pf && sv) {
            const int nb = cur ^ 1;
            *(uint4*)&Xa[nb][spid << 3]          = ((uint4*)hv)[0];
            *(uint4*)&Xa[nb][1584 + (spid << 3)] = ((uint4*)hv)[1];
            *(uint4*)&Xb[nb][spid << 3]          = ((uint4*)lv)[0];
            *(uint4*)&Xb[nb][1584 + (spid << 3)] = ((uint4*)lv)[1];
        }
        cur ^= 1;
    }

    const int x = (xh << 5) + l31;
#pragma unroll
    for (int r = 0; r < 16; r++) {
        int c2 = co0 + (wy << 5) + (r & 3) + ((r >> 2) << 3) + (g << 2);
        float v = fmaf(acc[r], bn[c2], bn[128 + c2]);
        v = v > 0.f ? v : 0.f;
        out_f32[(((size_t)b * 128 + c2) << 12) + (y << 6) + x] = v;
    }
}

// ---- CAM Gram via hi/lo MFMA, upper-triangle tiles + mirror write. --------
__global__ __launch_bounds__(256) void cam_energy_mfma(
    const unsigned short* __restrict__ bh, const unsigned short* __restrict__ bl,
    float* __restrict__ egy_part)
{
    const int t   = threadIdx.x;
    const int w   = t >> 6;
    const int ln  = t & 63;
    const int l31 = ln & 31;
    const int g   = ln >> 5;
    const int bx  = blockIdx.x;
    int i0c, j0c;
    if (bx < 4)      { i0c = 0; j0c = bx; }
    else if (bx < 7) { i0c = 1; j0c = bx - 3; }
    else if (bx < 9) { i0c = 2; j0c = bx - 5; }
    else             { i0c = 3; j0c = 3; }
    const int i0  = i0c << 5;
    const int j0  = j0c << 5;
    const int nseg = blockIdx.y;
    const int b   = blockIdx.z;

    __shared__ float red[4][64][17];

    const f32x16 zero = {0,0,0,0,0,0,0,0,0,0,0,0,0,0,0,0};
    f32x16 acc = zero;
    const int nb = (nseg << 9) + (w << 7) + (g << 3);
    const size_t ri = ((size_t)b * 128 + i0 + l31) << 12;
    const size_t rj = ((size_t)b * 128 + j0 + l31) << 12;

#pragma unroll
    for (int c = 0; c < 8; c++) {
        const int n0 = nb + (c << 4);
        short8 ah  = *(const short8*)(bh + ri + n0);
        short8 al  = *(const short8*)(bl + ri + n0);
        short8 bhf = *(const short8*)(bh + rj + n0);
        short8 blf = *(const short8*)(bl + rj + n0);
        acc = __builtin_amdgcn_mfma_f32_32x32x16_bf16(ah, bhf, acc, 0, 0, 0);
        acc = __builtin_amdgcn_mfma_f32_32x32x16_bf16(ah, blf, acc, 0, 0, 0);
        acc = __builtin_amdgcn_mfma_f32_32x32x16_bf16(al, bhf, acc, 0, 0, 0);
    }
#pragma unroll
    for (int r = 0; r < 16; r++) red[w][ln][r] = acc[r];
    __syncthreads();

    const int lane = t & 63;
    const int rq   = t >> 6;
    float* base = egy_part + (((size_t)(nseg * 8 + b)) << 14);
#pragma unroll
    for (int e = 0; e < 4; e++) {
        const int reg = (rq << 2) + e;
        float v = red[0][lane][reg] + red[1][lane][reg]
                + red[2][lane][reg] + red[3][lane][reg];
        const int i = i0 + (reg & 3) + ((reg >> 2) << 3) + ((lane >> 5) << 2);
        const int j = j0 + (lane & 31);
        base[i * 128 + j] = v;
        if (i0c != j0c) base[j * 128 + i] = v;   // Gram symmetry mirror
    }
}

// ---- CAM softmax of (rowmax - e), fused 8-seg reduce. grid (8, 8) ---------
__global__ __launch_bounds__(256) void cam_softmax_fused(
    const float* __restrict__ egy_part, float* __restrict__ egy)
{
    const int b   = blockIdx.x;
    const int rg  = blockIdx.y;
    const int t   = threadIdx.x;
    const int row = (rg << 4) + (t >> 4);
    const int jg  = t & 15;

    float e[8];
#pragma unroll
    for (int jj = 0; jj < 8; jj++) e[jj] = 0.f;
    for (int seg = 0; seg < 8; seg++) {
        const float* p = egy_part + (((size_t)(seg * 8 + b)) << 14) + row * 128 + (jg << 3);
#pragma unroll
        for (int jj = 0; jj < 8; jj++) e[jj] += p[jj];
    }
    float mn = e[0];
#pragma unroll
    for (int jj = 1; jj < 8; jj++) mn = fminf(mn, e[jj]);
#pragma unroll
    for (int k = 1; k < 16; k <<= 1) mn = fminf(mn, __shfl_xor(mn, k));
    float s = 0.f;
#pragma unroll
    for (int jj = 0; jj < 8; jj++) { float p = __expf(mn - e[jj]); e[jj] = p; s += p; }
#pragma unroll
    for (int k = 1; k < 16; k <<= 1) s += __shfl_xor(s, k);
    const float inv = 1.f / s;
    float* orow = egy + ((size_t)b << 14) + row * 128 + (jg << 3);
#pragma unroll
    for (int jj = 0; jj < 8; jj++) orow[jj] = e[jj] * inv;
}

// ---- PAM Q/K producer ----
__global__ __launch_bounds__(256) void pam_qk_1x1(
    const float* __restrict__ A, const float* __restrict__ Wb, const float* __restrict__ bb,
    const float* __restrict__ Wc, const float* __restrict__ bc,
    unsigned short* __restrict__ qt, unsigned short* __restrict__ kt)
{
    __shared__ float wl[2 * 16 * 128];
    __shared__ float bl[32];
    const int t = threadIdx.x;
    const int n = (blockIdx.x << 8) + t;
    const int b = blockIdx.y;
    for (int idx = t; idx < 2048; idx += 256) { wl[idx] = Wb[idx]; wl[2048 + idx] = Wc[idx]; }
    if (t < 16) { bl[t] = bb[t]; bl[16 + t] = bc[t]; }
    __syncthreads();
    float ab[16], ac[16];
#pragma unroll
    for (int k = 0; k < 16; k++) { ab[k] = 0.f; ac[k] = 0.f; }
    for (int chn = 0; chn < 128; ++chn) {
        float a = A[(((size_t)b * 128 + chn) << 12) + n];
#pragma unroll
        for (int k = 0; k < 16; k++) {
            ab[k] = fmaf(wl[k * 128 + chn], a, ab[k]);
            ac[k] = fmaf(wl[2048 + k * 128 + chn], a, ac[k]);
        }
    }
    unsigned short uq[16], uk[16];
#pragma unroll
    for (int k = 0; k < 16; k++) {
        uq[k] = f2bf(ab[k] + bl[k]);
        uk[k] = f2bf(ac[k] + bl[16 + k]);
    }
    size_t row = (size_t)b * 4096 + n;
    ((uint4*)qt)[row * 2 + 0] = ((uint4*)uq)[0];
    ((uint4*)qt)[row * 2 + 1] = ((uint4*)uq)[1];
    ((uint4*)kt)[row * 2 + 0] = ((uint4*)uk)[0];
    ((uint4*)kt)[row * 2 + 1] = ((uint4*)uk)[1];
}

// ---- PAM V producer ----
__global__ __launch_bounds__(256) void pam_v_1x1(
    const float* __restrict__ A, const float* __restrict__ Wd, const float* __restrict__ bd,
    unsigned short* __restrict__ vb)
{
    __shared__ float wl[32 * 128];
    __shared__ float bl[32];
    const int t   = threadIdx.x;
    const int n   = (blockIdx.x << 8) + t;
    const int co0 = blockIdx.y << 5;
    const int b   = blockIdx.z;
    for (int idx = t; idx < 4096; idx += 256) {
        int c2 = idx >> 7, chv = idx & 127;
        wl[idx] = Wd[(co0 + c2) * 128 + chv];
    }
    if (t < 32) bl[t] = bd[co0 + t];
    __syncthreads();
    float acc[32];
#pragma unroll
    for (int k = 0; k < 32; k++) acc[k] = 0.f;
    for (int chn = 0; chn < 128; ++chn) {
        float a = A[(((size_t)b * 128 + chn) << 12) + n];
#pragma unroll
        for (int k = 0; k < 32; k++) acc[k] = fmaf(wl[k * 128 + chn], a, acc[k]);
    }
#pragma unroll
    for (int k = 0; k < 32; k++)
        vb[(((size_t)b * 128 + co0 + k) << 12) + n] = f2bf(acc[k] + bl[k]);
}

// ---- PAM attention, MFMA, ONLINE softmax, n0=64 Q-tile --------------------
__global__ __launch_bounds__(256) void pam_attn_mfma(
    const unsigned short* __restrict__ qt, const unsigned short* __restrict__ kt,
    const unsigned short* __restrict__ vb,
    const float* __restrict__ alpha, const float* __restrict__ Y,
    unsigned short* __restrict__ outb)
{
    const int t  = threadIdx.x;
    const int w  = t >> 6;
    const int L  = t & 63;
    const int ln = L & 31;
    const int g  = L >> 5;
    const int b  = blockIdx.y;
    const int n0 = blockIdx.x << 6;
    const int c0 = w << 5;

    __shared__ unsigned short Pf[2][16 * 512];   // 32 KB
    __shared__ float red[2][4][64];              // 2 KB
    __shared__ float redS[4][64];                // 1 KB

    const f32x16 zero = {0,0,0,0,0,0,0,0,0,0,0,0,0,0,0,0};
    short8 q0 = *(const short8*)(qt + (((size_t)b * 4096 + n0 + ln) << 4) + (g << 3));
    short8 q1 = *(const short8*)(qt + (((size_t)b * 4096 + n0 + 32 + ln) << 4) + (g << 3));
    const float al = alpha[0];

    f32x16 acc0 = zero, acc1 = zero;
    float rs0 = 0.f, rs1 = 0.f;
    float mold0 = -3.0e38f, mold1 = -3.0e38f;

    int par = 0;
    for (int m0 = 0; m0 < 4096; m0 += 128) {
        const int mq = m0 + (w << 5);
        short8 kfrag = *(const short8*)(kt + (((size_t)b * 4096 + mq + ln) << 4) + (g << 3));
        f32x16 s0 = __builtin_amdgcn_mfma_f32_32x32x16_bf16(kfrag, q0, zero, 0, 0, 0);
        f32x16 s1 = __builtin_amdgcn_mfma_f32_32x32x16_bf16(kfrag, q1, zero, 0, 0, 0);

        float lm0 = s0[0], lm1 = s1[0];
#pragma unroll
        for (int r = 1; r < 16; r++) { lm0 = fmaxf(lm0, s0[r]); lm1 = fmaxf(lm1, s1[r]); }
        lm0 = fmaxf(lm0, __shfl_xor(lm0, 32));
        lm1 = fmaxf(lm1, __shfl_xor(lm1, 32));
        if (L < 32) { red[par][w][L] = lm0; red[par][w][32 + L] = lm1; }
        __syncthreads();                                   // B1: red[par] ready
        const float mb0 = fmaxf(fmaxf(red[par][0][ln], red[par][1][ln]),
                                fmaxf(red[par][2][ln], red[par][3][ln]));
        const float mb1 = fmaxf(fmaxf(red[par][0][32 + ln], red[par][1][32 + ln]),
                                fmaxf(red[par][2][32 + ln], red[par][3][32 + ln]));
        const float mnew0 = fmaxf(mold0, mb0);
        const float mnew1 = fmaxf(mold1, mb1);
        const float fs0 = __expf(mold0 - mnew0);
        const float fs1 = __expf(mold1 - mnew1);
        mold0 = mnew0; mold1 = mnew1;
        rs0 *= fs0; rs1 *= fs1;
#pragma unroll
        for (int r = 0; r < 16; r++) { acc0[r] *= fs0; acc1[r] *= fs1; }

        {
            float p[16];
#pragma unroll
            for (int r = 0; r < 16; r++) { p[r] = __expf(s0[r] - mnew0); rs0 += p[r]; }
            float xx[16];
#pragma unroll
            for (int r = 0; r < 16; r++) xx[r] = __shfl_xor(p[r], 32);
            unsigned short f0[8], f1[8];
#pragma unroll
            for (int i = 0; i < 4; i++) {
                f0[i]     = f2bf(g ? xx[4 + i]  : p[i]);
                f0[4 + i] = f2bf(g ? p[4 + i]   : xx[i]);
                f1[i]     = f2bf(g ? xx[12 + i] : p[8 + i]);
                f1[4 + i] = f2bf(g ? p[12 + i]  : xx[8 + i]);
            }
            *(short8*)(&Pf[par][((w << 2) + g) * 512 + (ln << 3)])     = *(short8*)f0;
            *(short8*)(&Pf[par][((w << 2) + 2 + g) * 512 + (ln << 3)]) = *(short8*)f1;
        }
        {
            float p[16];
#pragma unroll
            for (int r = 0; r < 16; r++) { p[r] = __expf(s1[r] - mnew1); rs1 += p[r]; }
            float xx[16];
#pragma unroll
            for (int r = 0; r < 16; r++) xx[r] = __shfl_xor(p[r], 32);
            unsigned short f0[8], f1[8];
#pragma unroll
            for (int i = 0; i < 4; i++) {
                f0[i]     = f2bf(g ? xx[4 + i]  : p[i]);
                f0[4 + i] = f2bf(g ? p[4 + i]   : xx[i]);
                f1[i]     = f2bf(g ? xx[12 + i] : p[8 + i]);
                f1[4 + i] = f2bf(g ? p[12 + i]  : xx[8 + i]);
            }
            *(short8*)(&Pf[par][((w << 2) + g) * 512 + 256 + (ln << 3)])     = *(short8*)f0;
            *(short8*)(&Pf[par][((w << 2) + 2 + g) * 512 + 256 + (ln << 3)]) = *(short8*)f1;
        }
        __syncthreads();                                   // B2: Pf[par] ready

#pragma unroll
        for (int kk = 0; kk < 8; kk++) {
            short8 vfrag = *(const short8*)(vb + (((size_t)b * 128 + c0 + ln) << 12)
                                               + m0 + (kk << 4) + (g << 3));
            short8 pf0 = *(const short8*)(&Pf[par][((kk << 1) + g) * 512 + (ln << 3)]);
            short8 pf1 = *(const short8*)(&Pf[par][((kk << 1) + g) * 512 + 256 + (ln << 3)]);
            acc0 = __builtin_amdgcn_mfma_f32_32x32x16_bf16(vfrag, pf0, acc0, 0, 0, 0);
            acc1 = __builtin_amdgcn_mfma_f32_32x32x16_bf16(vfrag, pf1, acc1, 0, 0, 0);
        }
        par ^= 1;
    }

    rs0 += __shfl_xor(rs0, 32);
    rs1 += __shfl_xor(rs1, 32);
    if (L < 32) { redS[w][L] = rs0; redS[w][32 + L] = rs1; }
    __syncthreads();
    const float inv0 = 1.f / (redS[0][ln] + redS[1][ln] + redS[2][ln] + redS[3][ln]);
    const float inv1 = 1.f / (redS[0][32 + ln] + redS[1][32 + ln]
                            + redS[2][32 + ln] + redS[3][32 + ln]);
#pragma unroll
    for (int r = 0; r < 16; r++) {
        int c = c0 + (r & 3) + ((r >> 2) << 3) + (g << 2);
        size_t idx0 = (((size_t)b * 128 + c) << 12) + n0 + ln;
        outb[idx0]      = f2bf(fmaf(al, acc0[r] * inv0, Y[idx0]));
        outb[idx0 + 32] = f2bf(fmaf(al, acc1[r] * inv1, Y[idx0 + 32]));
    }
}

// ---- CAM feat: emits hi/lo bf16 directly (feeds conv2c) -------------------
__global__ __launch_bounds__(256) void cam_feat(
    const float* __restrict__ attn, const float* __restrict__ Bf,
    const float* __restrict__ beta, unsigned short* __restrict__ oh,
    unsigned short* __restrict__ ol)
{
    const int t  = threadIdx.x;
    const int n  = (blockIdx.x << 8) + t;
    const int c0 = blockIdx.y << 5;
    const int b  = blockIdx.z;
    __shared__ float al[32 * 128];
    for (int idx = t; idx < 4096; idx += 256)
        al[idx] = attn[(size_t)b * 16384 + (c0 + (idx >> 7)) * 128 + (idx & 127)];
    __syncthreads();
    float acc[32];
#pragma unroll
    for (int k = 0; k < 32; k++) acc[k] = 0.f;
    for (int d = 0; d < 128; ++d) {
        float v = Bf[(((size_t)b * 128 + d) << 12) + n];
#pragma unroll
        for (int k = 0; k < 32; k++) acc[k] = fmaf(al[k * 128 + d], v, acc[k]);
    }
    float be = beta[0];
#pragma unroll
    for (int k = 0; k < 32; k++) {
        size_t idx = (((size_t)b * 128 + c0 + k) << 12) + n;
        float v = fmaf(be, acc[k], Bf[idx]);
        unsigned short hi = f2bf(v);
        oh[idx] = hi;
        ol[idx] = f2bf(v - bf2f(hi));
    }
}

// ---- Final heads ----
__global__ __launch_bounds__(256) void heads(
    const float* __restrict__ FP, const float* __restrict__ FC,
    const float* __restrict__ Wout, const float* __restrict__ bout,
    const float* __restrict__ Wp3, const float* __restrict__ bp3,
    const float* __restrict__ Wc3, const float* __restrict__ bc3,
    float* __restrict__ out)
{
    const int t = threadIdx.x;
    const int n = (blockIdx.x << 8) + t;
    const int b = blockIdx.y;
    __shared__ float wl[3 * 19 * 128];
    __shared__ float bl[3 * 19];
    for (int idx = t; idx < 2432; idx += 256) {
        wl[idx]        = Wout[idx];
        wl[2432 + idx] = Wp3[idx];
        wl[4864 + idx] = Wc3[idx];
    }
    if (t < 19) { bl[t] = bout[t]; bl[19 + t] = bp3[t]; bl[38 + t] = bc3[t]; }
    __syncthreads();
    float am[19], ap[19], ac[19];
#pragma unroll
    for (int o = 0; o < 19; o++) { am[o] = 0.f; ap[o] = 0.f; ac[o] = 0.f; }
    for (int chn = 0; chn < 128; ++chn) {
        float pv = FP[(((size_t)b * 128 + chn) << 12) + n];
        float cv = FC[(((size_t)b * 128 + chn) << 12) + n];
        float fv = pv + cv;
#pragma unroll
        for (int o = 0; o < 19; o++) {
            am[o] = fmaf(wl[o * 128 + chn], fv, am[o]);
            ap[o] = fmaf(wl[2432 + o * 128 + chn], pv, ap[o]);
            ac[o] = fmaf(wl[4864 + o * 128 + chn], cv, ac[o]);
        }
    }
    const size_t OS = (size_t)8 * 19 * 4096;
#pragma unroll
    for (int o = 0; o < 19; o++) {
        size_t base = (((size_t)b * 19 + o) << 12) + n;
        out[base]          = 1.f / (1.f + __expf(-(am[o] + bl[o])));
        out[OS + base]     = 1.f / (1.f + __expf(-(ap[o] + bl[19 + o])));
        out[2 * OS + base] = 1.f / (1.f + __expf(-(ac[o] + bl[38 + o])));
    }
}

extern "C" void kernel_launch(void* const* d_in, const int* in_sizes, int n_in,
                              void* d_out, int out_size, void* d_ws, size_t ws_size,
                              hipStream_t stream)
{
    const float* x     = (const float*)d_in[0];
    const float* Wp1   = (const float*)d_in[1];
    const float* bnp1  = (const float*)d_in[2];
    const float* Wc1   = (const float*)d_in[3];
    const float* bnc1  = (const float*)d_in[4];
    const float* Wb    = (const float*)d_in[5];
    const float* bb    = (const float*)d_in[6];
    const float* Wc    = (const float*)d_in[7];
    const float* bcv   = (const float*)d_in[8];
    const float* Wd    = (const float*)d_in[9];
    const float* bd    = (const float*)d_in[10];
    const float* alpha = (const float*)d_in[11];
    const float* beta  = (const float*)d_in[12];
    const float* Wp2   = (const float*)d_in[13];
    const float* bnp2  = (const float*)d_in[14];
    const float* Wc2   = (const float*)d_in[15];
    const float* bnc2  = (const float*)d_in[16];
    const float* Wout  = (const float*)d_in[17];
    const float* bo    = (const float*)d_in[18];
    const float* Wp3   = (const float*)d_in[19];
    const float* bp3   = (const float*)d_in[20];
    const float* Wc3   = (const float*)d_in[21];
    const float* bc3   = (const float*)d_in[22];
    float* out = (float*)d_out;

    char* ws = (char*)d_ws;
    const size_t MB = 1u << 20;
    const size_t W1SZ = (size_t)32 * 18432 * 2;
    const size_t W2SZ = (size_t)8 * 18432 * 2;
    float*          bufA     = (float*)(ws);
    float*          bufB     = (float*)(ws + 16 * MB);
    unsigned short* vb       = (unsigned short*)(ws + 32 * MB);  // 8MB
    float*          egy_part = (float*)(ws + 40 * MB);           // 4MB
    float*          bufD     = (float*)(ws + 32 * MB);           // conv2p out (later)
    unsigned short* bh       = (unsigned short*)(ws + 48 * MB);  // 8MB
    unsigned short* blo      = (unsigned short*)(ws + 56 * MB);  // 8MB
    unsigned short* pam_bf   = (unsigned short*)(ws + 48 * MB);  // after Gram
    unsigned short* c2h      = (unsigned short*)(ws + 48 * MB);  // after conv2p
    unsigned short* c2l      = (unsigned short*)(ws + 56 * MB);
    unsigned short* qt       = (unsigned short*)(ws + 64 * MB);
    unsigned short* kt       = (unsigned short*)(ws + 65 * MB);
    float*          egy      = (float*)(ws + 66 * MB + (1u << 17));
    unsigned short* wp1      = (unsigned short*)(ws + 67 * MB);
    unsigned short* wc1h     = (unsigned short*)(ws + 67 * MB + W1SZ);
    unsigned short* wc1l     = (unsigned short*)(ws + 67 * MB + 2 * W1SZ);
    unsigned short* wp2      = (unsigned short*)(ws + 67 * MB + 3 * W1SZ);
    unsigned short* wc2h     = (unsigned short*)(ws + 67 * MB + 3 * W1SZ + W2SZ);
    unsigned short* wc2l     = (unsigned short*)(ws + 67 * MB + 3 * W1SZ + 2 * W2SZ);

    dim3 blk(256);
    const int n1 = 32 * 18432;
    const int n2 = 8 * 18432;
    wpack_kernel<<<dim3((n1 + 255) / 256), blk, 0, stream>>>(Wp1, wp1, 512, n1);
    wpack_kernel<<<dim3((n2 + 255) / 256), blk, 0, stream>>>(Wp2, wp2, 128, n2);
    wpack_split_kernel<<<dim3((n1 + 255) / 256), blk, 0, stream>>>(Wc1, wc1h, wc1l, 512, n1);
    wpack_split_kernel<<<dim3((n2 + 255) / 256), blk, 0, stream>>>(Wc2, wc2h, wc2l, 128, n2);

    // fused conv1p + conv1c (W in LDS via global_load_lds)
    conv3x3_merged<<<dim3(64, 2, 8), blk, 0, stream>>>(x, wp1, wc1h, wc1l, bnp1, bnc1,
                                                       bufA, bufB, bh, blo);
    // CAM Gram (triangle) + softmax
    cam_energy_mfma<<<dim3(10, 8, 8), blk, 0, stream>>>(bh, blo, egy_part);
    cam_softmax_fused<<<dim3(8, 8), blk, 0, stream>>>(egy_part, egy);
    // PAM
    pam_qk_1x1<<<dim3(16, 8), blk, 0, stream>>>(bufA, Wb, bb, Wc, bcv, qt, kt);
    pam_v_1x1<<<dim3(16, 4, 8), blk, 0, stream>>>(bufA, Wd, bd, vb);
    pam_attn_mfma<<<dim3(64, 8), blk, 0, stream>>>(qt, kt, vb, alpha, bufA, pam_bf);
    // conv2p (reads pam_bf, writes bufD over vb/egy_part which are now dead)
    conv3x3_bf<<<dim3(64, 2, 8), blk, 0, stream>>>(pam_bf, 128, wp2, bnp2, bufD);
    // CAM tail (c2h/c2l overwrite pam_bf region after conv2p consumed it)
    cam_feat<<<dim3(16, 4, 8), blk, 0, stream>>>(egy, bufB, beta, c2h, c2l);
    conv3x3_hilo_bf<<<dim3(64, 2, 8), blk, 0, stream>>>(c2h, c2l, 128, wc2h, wc2l, bnc2, bufA);
    // fusion + heads
    heads<<<dim3(16, 8), blk, 0, stream>>>(bufD, bufA, Wout, bo, Wp3, bp3, Wc3, bc3, out);
}

// Round 9
// 748.235 us; speedup vs baseline: 1.0175x; 1.0175x over previous
//
#include <hip/hip_runtime.h>
#include <math.h>

// ---------------------------------------------------------------------------
// DAHead: B=8, Cin=512, Ci=128, H=W=64, N=4096, Ck=16, NC=19.
// R14: convs -> 64px-wide waves (2 accumulator pairs): each W fragment feeds
//   2 MFMAs (b0,b1 x-halves), halving W operand bytes per MFMA. All conv
//   datapoints (R6-R13) fit "per-chunk time = W bytes / ~30B/cyc L1-port
//   (or /128B/cyc LDS)"; occupancy >16 waves/CU never helped. Block = 1 row
//   x 128 co (4 waves = co-slices), grid (64,1,8): X staged once per block
//   serves all co. W per-tap global loads (no reg-preload bloat: R7/R11
//   lesson), 1 barrier/chunk, bit-identical per-accumulator MFMA order.
// Everything else = R12 (730us best): pam_attn n0=64, triangle Gram, etc.
// ws (byte offsets): identical to R12.
// ---------------------------------------------------------------------------

typedef __attribute__((ext_vector_type(8)))  short short8;
typedef __attribute__((ext_vector_type(16))) float f32x16;

__device__ inline unsigned short f2bf(float f) {
    union { float f; unsigned u; } v; v.f = f;
    unsigned r = v.u + 0x7fffu + ((v.u >> 16) & 1u);   // RNE
    return (unsigned short)(r >> 16);
}
__device__ inline float bf2f(unsigned short h) {
    union { unsigned u; float f; } v; v.u = ((unsigned)h) << 16;
    return v.f;
}

// ---- weight prepack: W[co][cin][9] fp32 ->
//      wpack[chunk][tap][g(=ci>>3)][co128][ci8]  (bf16) ----------------------
__global__ __launch_bounds__(256) void wpack_kernel(
    const float* __restrict__ W, unsigned short* __restrict__ wp, int Cin, int total)
{
    int idx = blockIdx.x * 256 + threadIdx.x;
    if (idx >= total) return;
    int chunk = idx / 18432;
    int rem   = idx - chunk * 18432;
    int tap   = rem >> 11;
    int rem2  = rem & 2047;
    int g     = rem2 >> 10;
    int co    = (rem2 >> 3) & 127;
    int ci8   = rem2 & 7;
    int cin   = (chunk << 4) + (g << 3) + ci8;
    wp[idx] = f2bf(W[((size_t)co * Cin + cin) * 9 + tap]);
}

__global__ __launch_bounds__(256) void wpack_split_kernel(
    const float* __restrict__ W, unsigned short* __restrict__ wph,
    unsigned short* __restrict__ wpl, int Cin, int total)
{
    int idx = blockIdx.x * 256 + threadIdx.x;
    if (idx >= total) return;
    int chunk = idx / 18432;
    int rem   = idx - chunk * 18432;
    int tap   = rem >> 11;
    int rem2  = rem & 2047;
    int g     = rem2 >> 10;
    int co    = (rem2 >> 3) & 127;
    int ci8   = rem2 & 7;
    int cin   = (chunk << 4) + (g << 3) + ci8;
    float w = W[((size_t)co * Cin + cin) * 9 + tap];
    unsigned short hi = f2bf(w);
    wph[idx] = hi;
    wpl[idx] = f2bf(w - bf2f(hi));
}

// ---- FUSED conv1: plain (Wp1 -> bufA) + hilo (Wc1 -> bufB,bh,bl) ----------
// 256 thr / 4 waves = 4 co-slices; wave tile 64px x 32co; block 1 row x 128co.
// grid (64, 1, 8) = 512 blocks. LDS 25,344 B. Each W fragment feeds 2 MFMAs.
__global__ __launch_bounds__(256, 2) void conv3x3_merged(
    const float* __restrict__ xin,
    const unsigned short* __restrict__ wpp,
    const unsigned short* __restrict__ wph, const unsigned short* __restrict__ wpl,
    const float* __restrict__ bnp, const float* __restrict__ bnc,
    float* __restrict__ outP, float* __restrict__ outC,
    unsigned short* __restrict__ outh, unsigned short* __restrict__ outl)
{
    const int t   = threadIdx.x;
    const int w2  = t >> 6;           // co slice 0..3
    const int ln  = t & 63;
    const int l31 = ln & 31;
    const int g   = ln >> 5;
    const int y   = blockIdx.x;       // output row
    const int b   = blockIdx.z;

    const int sr   = t >> 6;          // 0..2
    const int sx   = t & 63;
    const int sgy  = y - 1 + sr;
    const bool sv  = (t < 192) && ((unsigned)sgy < 64u);
    const int spid = sr * 66 + sx + 1;

    __shared__ __align__(16) unsigned short Xh[2][3168];   // [buf][g*1584 + pid*8]
    __shared__ __align__(16) unsigned short Xo[2][3168];   // 25,344 B

    for (int i = t; i < 792; i += 256) {
        uint4 z; z.x = 0; z.y = 0; z.z = 0; z.w = 0;
        ((uint4*)Xh)[i] = z;
        ((uint4*)Xo)[i] = z;
    }

    const int co = (w2 << 5) + l31;
    const unsigned short* wPb = wpp + (size_t)(g << 10) + ((size_t)co << 3);
    const unsigned short* wHb = wph + (size_t)(g << 10) + ((size_t)co << 3);
    const unsigned short* wLb = wpl + (size_t)(g << 10) + ((size_t)co << 3);
    const float* xsrc = xin + ((size_t)b << 21) + (sgy << 6) + sx;

    const f32x16 zero = {0,0,0,0,0,0,0,0,0,0,0,0,0,0,0,0};
    f32x16 ap0 = zero, ap1 = zero, ac0 = zero, ac1 = zero;

    float xv[16];
    if (sv) {
#pragma unroll
        for (int c = 0; c < 16; c++) xv[c] = xsrc[(size_t)c << 12];
    }
    __syncthreads();   // zero-init done

    if (sv) {
        unsigned short th[16], tl[16];
#pragma unroll
        for (int c = 0; c < 16; c++) {
            unsigned short hi = f2bf(xv[c]);
            th[c] = hi; tl[c] = f2bf(xv[c] - bf2f(hi));
        }
        *(uint4*)&Xh[0][spid << 3]          = ((uint4*)th)[0];
        *(uint4*)&Xh[0][1584 + (spid << 3)] = ((uint4*)th)[1];
        *(uint4*)&Xo[0][spid << 3]          = ((uint4*)tl)[0];
        *(uint4*)&Xo[0][1584 + (spid << 3)] = ((uint4*)tl)[1];
    }

    int cur = 0;
    for (int ch = 0; ch < 32; ++ch) {
        __syncthreads();
        const bool pf = (ch < 31);
        if (pf && sv) {
#pragma unroll
            for (int c = 0; c < 16; c++)
                xv[c] = xsrc[((size_t)(ch + 1) << 16) + ((size_t)c << 12)];
        }
        const size_t wo = (size_t)ch * 18432;
#pragma unroll 3
        for (int tap = 0; tap < 9; ++tap) {
            const int dy = tap / 3, dx = tap - dy * 3;
            const int xi0 = (g ? 1584 : 0) + (((dy * 66) + l31 + dx) << 3);
            const int xi1 = xi0 + 256;
            short8 vap = *(const short8*)(wPb + wo + tap * 2048);
            short8 vah = *(const short8*)(wHb + wo + tap * 2048);
            short8 val = *(const short8*)(wLb + wo + tap * 2048);
            short8 b0h = *(const short8*)&Xh[cur][xi0];
            short8 b1h = *(const short8*)&Xh[cur][xi1];
            short8 b0l = *(const short8*)&Xo[cur][xi0];
            short8 b1l = *(const short8*)&Xo[cur][xi1];
            ap0 = __builtin_amdgcn_mfma_f32_32x32x16_bf16(vap, b0h, ap0, 0, 0, 0);
            ap1 = __builtin_amdgcn_mfma_f32_32x32x16_bf16(vap, b1h, ap1, 0, 0, 0);
            ac0 = __builtin_amdgcn_mfma_f32_32x32x16_bf16(vah, b0h, ac0, 0, 0, 0);
            ac1 = __builtin_amdgcn_mfma_f32_32x32x16_bf16(vah, b1h, ac1, 0, 0, 0);
            ac0 = __builtin_amdgcn_mfma_f32_32x32x16_bf16(vah, b0l, ac0, 0, 0, 0);
            ac1 = __builtin_amdgcn_mfma_f32_32x32x16_bf16(vah, b1l, ac1, 0, 0, 0);
            ac0 = __builtin_amdgcn_mfma_f32_32x32x16_bf16(val, b0h, ac0, 0, 0, 0);
            ac1 = __builtin_amdgcn_mfma_f32_32x32x16_bf16(val, b1h, ac1, 0, 0, 0);
        }
        if (pf && sv) {
            unsigned short th[16], tl[16];
#pragma unroll
            for (int c = 0; c < 16; c++) {
                unsigned short hi = f2bf(xv[c]);
                th[c] = hi; tl[c] = f2bf(xv[c] - bf2f(hi));
            }
            const int nb = cur ^ 1;
            *(uint4*)&Xh[nb][spid << 3]          = ((uint4*)th)[0];
            *(uint4*)&Xh[nb][1584 + (spid << 3)] = ((uint4*)th)[1];
            *(uint4*)&Xo[nb][spid << 3]          = ((uint4*)tl)[0];
            *(uint4*)&Xo[nb][1584 + (spid << 3)] = ((uint4*)tl)[1];
        }
        cur ^= 1;
    }

#pragma unroll
    for (int j = 0; j < 2; j++) {
        const f32x16 aP = j ? ap1 : ap0;
        const f32x16 aC = j ? ac1 : ac0;
        const int x = (j << 5) + l31;
#pragma unroll
        for (int r = 0; r < 16; r++) {
            int c2 = (w2 << 5) + (r & 3) + ((r >> 2) << 3) + (g << 2);
            size_t o = (((size_t)b * 128 + c2) << 12) + (y << 6) + x;
            float vp = fmaf(aP[r], bnp[c2], bnp[128 + c2]);
            vp = vp > 0.f ? vp : 0.f;
            outP[o] = vp;
            float vc = fmaf(aC[r], bnc[c2], bnc[128 + c2]);
            vc = vc > 0.f ? vc : 0.f;
            outC[o] = vc;
            unsigned short hi = f2bf(vc);
            outh[o] = hi;
            outl[o] = f2bf(vc - bf2f(hi));
        }
    }
}

// ---- plain 3x3 conv, bf16 input (conv2p). 64px waves. grid (64,1,8) -------
__global__ __launch_bounds__(256, 2) void conv3x3_bf(
    const unsigned short* __restrict__ xin, int Cin,
    const unsigned short* __restrict__ wpk, const float* __restrict__ bn,
    float* __restrict__ out_f32)
{
    const int t   = threadIdx.x;
    const int w2  = t >> 6;
    const int ln  = t & 63;
    const int l31 = ln & 31;
    const int g   = ln >> 5;
    const int y   = blockIdx.x;
    const int b   = blockIdx.z;

    const int sr   = t >> 6;
    const int sx   = t & 63;
    const int sgy  = y - 1 + sr;
    const bool sv  = (t < 192) && ((unsigned)sgy < 64u);
    const int spid = sr * 66 + sx + 1;

    __shared__ __align__(16) unsigned short Xl[2][3168];   // 12,672 B

    for (int i = t; i < 792; i += 256) {
        uint4 z; z.x = 0; z.y = 0; z.z = 0; z.w = 0;
        ((uint4*)Xl)[i] = z;
    }

    const int co = (w2 << 5) + l31;
    const unsigned short* wB = wpk + (size_t)(g << 10) + ((size_t)co << 3);
    const unsigned short* xsrc = xin + (((size_t)b * Cin) << 12) + (sgy << 6) + sx;

    const f32x16 zero = {0,0,0,0,0,0,0,0,0,0,0,0,0,0,0,0};
    f32x16 acc0 = zero, acc1 = zero;

    unsigned short xv[16];
    if (sv) {
#pragma unroll
        for (int c = 0; c < 16; c++) xv[c] = xsrc[(size_t)c << 12];
    }
    __syncthreads();

    if (sv) {
        *(uint4*)&Xl[0][spid << 3]          = ((uint4*)xv)[0];
        *(uint4*)&Xl[0][1584 + (spid << 3)] = ((uint4*)xv)[1];
    }

    const int nchunks = Cin >> 4;
    int cur = 0;
    for (int ch = 0; ch < nchunks; ++ch) {
        __syncthreads();
        const bool pf = (ch < nchunks - 1);
        if (pf && sv) {
#pragma unroll
            for (int c = 0; c < 16; c++)
                xv[c] = xsrc[((size_t)(ch + 1) << 16) + ((size_t)c << 12)];
        }
        const size_t wo = (size_t)ch * 18432;
#pragma unroll 3
        for (int tap = 0; tap < 9; ++tap) {
            const int dy = tap / 3, dx = tap - dy * 3;
            const int xi0 = (g ? 1584 : 0) + (((dy * 66) + l31 + dx) << 3);
            short8 a  = *(const short8*)(wB + wo + tap * 2048);
            short8 b0 = *(const short8*)&Xl[cur][xi0];
            short8 b1 = *(const short8*)&Xl[cur][xi0 + 256];
            acc0 = __builtin_amdgcn_mfma_f32_32x32x16_bf16(a, b0, acc0, 0, 0, 0);
            acc1 = __builtin_amdgcn_mfma_f32_32x32x16_bf16(a, b1, acc1, 0, 0, 0);
        }
        if (pf && sv) {
            const int nb = cur ^ 1;
            *(uint4*)&Xl[nb][spid << 3]          = ((uint4*)xv)[0];
            *(uint4*)&Xl[nb][1584 + (spid << 3)] = ((uint4*)xv)[1];
        }
        cur ^= 1;
    }

#pragma unroll
    for (int j = 0; j < 2; j++) {
        const f32x16 a = j ? acc1 : acc0;
        const int x = (j << 5) + l31;
#pragma unroll
        for (int r = 0; r < 16; r++) {
            int c2 = (w2 << 5) + (r & 3) + ((r >> 2) << 3) + (g << 2);
            float v = fmaf(a[r], bn[c2], bn[128 + c2]);
            v = v > 0.f ? v : 0.f;
            out_f32[(((size_t)b * 128 + c2) << 12) + (y << 6) + x] = v;
        }
    }
}

// ---- hilo 3x3 conv, pre-split bf16 inputs (conv2c). 64px waves. -----------
__global__ __launch_bounds__(256, 2) void conv3x3_hilo_bf(
    const unsigned short* __restrict__ xhg, const unsigned short* __restrict__ xlg,
    int Cin, const unsigned short* __restrict__ wph, const unsigned short* __restrict__ wpl,
    const float* __restrict__ bn, float* __restrict__ out_f32)
{
    const int t   = threadIdx.x;
    const int w2  = t >> 6;
    const int ln  = t & 63;
    const int l31 = ln & 31;
    const int g   = ln >> 5;
    const int y   = blockIdx.x;
    const int b   = blockIdx.z;

    const int sr   = t >> 6;
    const int sx   = t & 63;
    const int sgy  = y - 1 + sr;
    const bool sv  = (t < 192) && ((unsigned)sgy < 64u);
    const int spid = sr * 66 + sx + 1;

    __shared__ __align__(16) unsigned short Xa[2][3168];
    __shared__ __align__(16) unsigned short Xb[2][3168];   // 25,344 B

    for (int i = t; i < 792; i += 256) {
        uint4 z; z.x = 0; z.y = 0; z.z = 0; z.w = 0;
        ((uint4*)Xa)[i] = z;
        ((uint4*)Xb)[i] = z;
    }

    const int co = (w2 << 5) + l31;
    const unsigned short* wHb = wph + (size_t)(g << 10) + ((size_t)co << 3);
    const unsigned short* wLb = wpl + (size_t)(g << 10) + ((size_t)co << 3);
    const unsigned short* hsrc = xhg + (((size_t)b * Cin) << 12) + (sgy << 6) + sx;
    const unsigned short* lsrc = xlg + (((size_t)b * Cin) << 12) + (sgy << 6) + sx;

    const f32x16 zero = {0,0,0,0,0,0,0,0,0,0,0,0,0,0,0,0};
    f32x16 acc0 = zero, acc1 = zero;

    unsigned short hv[16], lv[16];
    if (sv) {
#pragma unroll
        for (int c = 0; c < 16; c++) { hv[c] = hsrc[(size_t)c << 12]; lv[c] = lsrc[(size_t)c << 12]; }
    }
    __syncthreads();

    if (sv) {
        *(uint4*)&Xa[0][spid << 3]          = ((uint4*)hv)[0];
        *(uint4*)&Xa[0][1584 + (spid << 3)] = ((uint4*)hv)[1];
        *(uint4*)&Xb[0][spid << 3]          = ((uint4*)lv)[0];
        *(uint4*)&Xb[0][1584 + (spid << 3)] = ((uint4*)lv)[1];
    }

    const int nchunks = Cin >> 4;
    int cur = 0;
    for (int ch = 0; ch < nchunks; ++ch) {
        __syncthreads();
        const bool pf = (ch < nchunks - 1);
        if (pf && sv) {
#pragma unroll
            for (int c = 0; c < 16; c++) {
                hv[c] = hsrc[((size_t)(ch + 1) << 16) + ((size_t)c << 12)];
                lv[c] = lsrc[((size_t)(ch + 1) << 16) + ((size_t)c << 12)];
            }
        }
        const size_t wo = (size_t)ch * 18432;
#pragma unroll 3
        for (int tap = 0; tap < 9; ++tap) {
            const int dy = tap / 3, dx = tap - dy * 3;
            const int xi0 = (g ? 1584 : 0) + (((dy * 66) + l31 + dx) << 3);
            const int xi1 = xi0 + 256;
            short8 ah  = *(const short8*)(wHb + wo + tap * 2048);
            short8 al  = *(const short8*)(wLb + wo + tap * 2048);
            short8 b0h = *(const short8*)&Xa[cur][xi0];
            short8 b1h = *(const short8*)&Xa[cur][xi1];
            short8 b0l = *(const short8*)&Xb[cur][xi0];
            short8 b1l = *(const short8*)&Xb[cur][xi1];
            acc0 = __builtin_amdgcn_mfma_f32_32x32x16_bf16(ah, b0h, acc0, 0, 0, 0);
            acc1 = __builtin_amdgcn_mfma_f32_32x32x16_bf16(ah, b1h, acc1, 0, 0, 0);
            acc0 = __builtin_amdgcn_mfma_f32_32x32x16_bf16(ah, b0l, acc0, 0, 0, 0);
            acc1 = __builtin_amdgcn_mfma_f32_32x32x16_bf16(ah, b1l, acc1, 0, 0, 0);
            acc0 = __builtin_amdgcn_mfma_f32_32x32x16_bf16(al, b0h, acc0, 0, 0, 0);
            acc1 = __builtin_amdgcn_mfma_f32_32x32x16_bf16(al, b1h, acc1, 0, 0, 0);
        }
        if (pf && sv) {
            const int nb = cur ^ 1;
            *(uint4*)&Xa[nb][spid << 3]          = ((uint4*)hv)[0];
            *(uint4*)&Xa[nb][1584 + (spid << 3)] = ((uint4*)hv)[1];
            *(uint4*)&Xb[nb][spid << 3]          = ((uint4*)lv)[0];
            *(uint4*)&Xb[nb][1584 + (spid << 3)] = ((uint4*)lv)[1];
        }
        cur ^= 1;
    }

#pragma unroll
    for (int j = 0; j < 2; j++) {
        const f32x16 a = j ? acc1 : acc0;
        const int x = (j << 5) + l31;
#pragma unroll
        for (int r = 0; r < 16; r++) {
            int c2 = (w2 << 5) + (r & 3) + ((r >> 2) << 3) + (g << 2);
            float v = fmaf(a[r], bn[c2], bn[128 + c2]);
            v = v > 0.f ? v : 0.f;
            out_f32[(((size_t)b * 128 + c2) << 12) + (y << 6) + x] = v;
        }
    }
}

// ---- CAM Gram via hi/lo MFMA, upper-triangle tiles + mirror write. --------
__global__ __launch_bounds__(256) void cam_energy_mfma(
    const unsigned short* __restrict__ bh, const unsigned short* __restrict__ bl,
    float* __restrict__ egy_part)
{
    const int t   = threadIdx.x;
    const int w   = t >> 6;
    const int ln  = t & 63;
    const int l31 = ln & 31;
    const int g   = ln >> 5;
    const int bx  = blockIdx.x;
    int i0c, j0c;
    if (bx < 4)      { i0c = 0; j0c = bx; }
    else if (bx < 7) { i0c = 1; j0c = bx - 3; }
    else if (bx < 9) { i0c = 2; j0c = bx - 5; }
    else             { i0c = 3; j0c = 3; }
    const int i0  = i0c << 5;
    const int j0  = j0c << 5;
    const int nseg = blockIdx.y;
    const int b   = blockIdx.z;

    __shared__ float red[4][64][17];

    const f32x16 zero = {0,0,0,0,0,0,0,0,0,0,0,0,0,0,0,0};
    f32x16 acc = zero;
    const int nb = (nseg << 9) + (w << 7) + (g << 3);
    const size_t ri = ((size_t)b * 128 + i0 + l31) << 12;
    const size_t rj = ((size_t)b * 128 + j0 + l31) << 12;

#pragma unroll
    for (int c = 0; c < 8; c++) {
        const int n0 = nb + (c << 4);
        short8 ah  = *(const short8*)(bh + ri + n0);
        short8 al  = *(const short8*)(bl + ri + n0);
        short8 bhf = *(const short8*)(bh + rj + n0);
        short8 blf = *(const short8*)(bl + rj + n0);
        acc = __builtin_amdgcn_mfma_f32_32x32x16_bf16(ah, bhf, acc, 0, 0, 0);
        acc = __builtin_amdgcn_mfma_f32_32x32x16_bf16(ah, blf, acc, 0, 0, 0);
        acc = __builtin_amdgcn_mfma_f32_32x32x16_bf16(al, bhf, acc, 0, 0, 0);
    }
#pragma unroll
    for (int r = 0; r < 16; r++) red[w][ln][r] = acc[r];
    __syncthreads();

    const int lane = t & 63;
    const int rq   = t >> 6;
    float* base = egy_part + (((size_t)(nseg * 8 + b)) << 14);
#pragma unroll
    for (int e = 0; e < 4; e++) {
        const int reg = (rq << 2) + e;
        float v = red[0][lane][reg] + red[1][lane][reg]
                + red[2][lane][reg] + red[3][lane][reg];
        const int i = i0 + (reg & 3) + ((reg >> 2) << 3) + ((lane >> 5) << 2);
        const int j = j0 + (lane & 31);
        base[i * 128 + j] = v;
        if (i0c != j0c) base[j * 128 + i] = v;   // Gram symmetry mirror
    }
}

// ---- CAM softmax of (rowmax - e), fused 8-seg reduce. grid (8, 8) ---------
__global__ __launch_bounds__(256) void cam_softmax_fused(
    const float* __restrict__ egy_part, float* __restrict__ egy)
{
    const int b   = blockIdx.x;
    const int rg  = blockIdx.y;
    const int t   = threadIdx.x;
    const int row = (rg << 4) + (t >> 4);
    const int jg  = t & 15;

    float e[8];
#pragma unroll
    for (int jj = 0; jj < 8; jj++) e[jj] = 0.f;
    for (int seg = 0; seg < 8; seg++) {
        const float* p = egy_part + (((size_t)(seg * 8 + b)) << 14) + row * 128 + (jg << 3);
#pragma unroll
        for (int jj = 0; jj < 8; jj++) e[jj] += p[jj];
    }
    float mn = e[0];
#pragma unroll
    for (int jj = 1; jj < 8; jj++) mn = fminf(mn, e[jj]);
#pragma unroll
    for (int k = 1; k < 16; k <<= 1) mn = fminf(mn, __shfl_xor(mn, k));
    float s = 0.f;
#pragma unroll
    for (int jj = 0; jj < 8; jj++) { float p = __expf(mn - e[jj]); e[jj] = p; s += p; }
#pragma unroll
    for (int k = 1; k < 16; k <<= 1) s += __shfl_xor(s, k);
    const float inv = 1.f / s;
    float* orow = egy + ((size_t)b << 14) + row * 128 + (jg << 3);
#pragma unroll
    for (int jj = 0; jj < 8; jj++) orow[jj] = e[jj] * inv;
}

// ---- PAM Q/K producer ----
__global__ __launch_bounds__(256) void pam_qk_1x1(
    const float* __restrict__ A, const float* __restrict__ Wb, const float* __restrict__ bb,
    const float* __restrict__ Wc, const float* __restrict__ bc,
    unsigned short* __restrict__ qt, unsigned short* __restrict__ kt)
{
    __shared__ float wl[2 * 16 * 128];
    __shared__ float bl[32];
    const int t = threadIdx.x;
    const int n = (blockIdx.x << 8) + t;
    const int b = blockIdx.y;
    for (int idx = t; idx < 2048; idx += 256) { wl[idx] = Wb[idx]; wl[2048 + idx] = Wc[idx]; }
    if (t < 16) { bl[t] = bb[t]; bl[16 + t] = bc[t]; }
    __syncthreads();
    float ab[16], ac[16];
#pragma unroll
    for (int k = 0; k < 16; k++) { ab[k] = 0.f; ac[k] = 0.f; }
    for (int chn = 0; chn < 128; ++chn) {
        float a = A[(((size_t)b * 128 + chn) << 12) + n];
#pragma unroll
        for (int k = 0; k < 16; k++) {
            ab[k] = fmaf(wl[k * 128 + chn], a, ab[k]);
            ac[k] = fmaf(wl[2048 + k * 128 + chn], a, ac[k]);
        }
    }
    unsigned short uq[16], uk[16];
#pragma unroll
    for (int k = 0; k < 16; k++) {
        uq[k] = f2bf(ab[k] + bl[k]);
        uk[k] = f2bf(ac[k] + bl[16 + k]);
    }
    size_t row = (size_t)b * 4096 + n;
    ((uint4*)qt)[row * 2 + 0] = ((uint4*)uq)[0];
    ((uint4*)qt)[row * 2 + 1] = ((uint4*)uq)[1];
    ((uint4*)kt)[row * 2 + 0] = ((uint4*)uk)[0];
    ((uint4*)kt)[row * 2 + 1] = ((uint4*)uk)[1];
}

// ---- PAM V producer ----
__global__ __launch_bounds__(256) void pam_v_1x1(
    const float* __restrict__ A, const float* __restrict__ Wd, const float* __restrict__ bd,
    unsigned short* __restrict__ vb)
{
    __shared__ float wl[32 * 128];
    __shared__ float bl[32];
    const int t   = threadIdx.x;
    const int n   = (blockIdx.x << 8) + t;
    const int co0 = blockIdx.y << 5;
    const int b   = blockIdx.z;
    for (int idx = t; idx < 4096; idx += 256) {
        int c2 = idx >> 7, chv = idx & 127;
        wl[idx] = Wd[(co0 + c2) * 128 + chv];
    }
    if (t < 32) bl[t] = bd[co0 + t];
    __syncthreads();
    float acc[32];
#pragma unroll
    for (int k = 0; k < 32; k++) acc[k] = 0.f;
    for (int chn = 0; chn < 128; ++chn) {
        float a = A[(((size_t)b * 128 + chn) << 12) + n];
#pragma unroll
        for (int k = 0; k < 32; k++) acc[k] = fmaf(wl[k * 128 + chn], a, acc[k]);
    }
#pragma unroll
    for (int k = 0; k < 32; k++)
        vb[(((size_t)b * 128 + co0 + k) << 12) + n] = f2bf(acc[k] + bl[k]);
}

// ---- PAM attention, MFMA, ONLINE softmax, n0=64 Q-tile --------------------
__global__ __launch_bounds__(256) void pam_attn_mfma(
    const unsigned short* __restrict__ qt, const unsigned short* __restrict__ kt,
    const unsigned short* __restrict__ vb,
    const float* __restrict__ alpha, const float* __restrict__ Y,
    unsigned short* __restrict__ outb)
{
    const int t  = threadIdx.x;
    const int w  = t >> 6;
    const int L  = t & 63;
    const int ln = L & 31;
    const int g  = L >> 5;
    const int b  = blockIdx.y;
    const int n0 = blockIdx.x << 6;
    const int c0 = w << 5;

    __shared__ unsigned short Pf[2][16 * 512];   // 32 KB
    __shared__ float red[2][4][64];              // 2 KB
    __shared__ float redS[4][64];                // 1 KB

    const f32x16 zero = {0,0,0,0,0,0,0,0,0,0,0,0,0,0,0,0};
    short8 q0 = *(const short8*)(qt + (((size_t)b * 4096 + n0 + ln) << 4) + (g << 3));
    short8 q1 = *(const short8*)(qt + (((size_t)b * 4096 + n0 + 32 + ln) << 4) + (g << 3));
    const float al = alpha[0];

    f32x16 acc0 = zero, acc1 = zero;
    float rs0 = 0.f, rs1 = 0.f;
    float mold0 = -3.0e38f, mold1 = -3.0e38f;

    int par = 0;
    for (int m0 = 0; m0 < 4096; m0 += 128) {
        const int mq = m0 + (w << 5);
        short8 kfrag = *(const short8*)(kt + (((size_t)b * 4096 + mq + ln) << 4) + (g << 3));
        f32x16 s0 = __builtin_amdgcn_mfma_f32_32x32x16_bf16(kfrag, q0, zero, 0, 0, 0);
        f32x16 s1 = __builtin_amdgcn_mfma_f32_32x32x16_bf16(kfrag, q1, zero, 0, 0, 0);

        float lm0 = s0[0], lm1 = s1[0];
#pragma unroll
        for (int r = 1; r < 16; r++) { lm0 = fmaxf(lm0, s0[r]); lm1 = fmaxf(lm1, s1[r]); }
        lm0 = fmaxf(lm0, __shfl_xor(lm0, 32));
        lm1 = fmaxf(lm1, __shfl_xor(lm1, 32));
        if (L < 32) { red[par][w][L] = lm0; red[par][w][32 + L] = lm1; }
        __syncthreads();                                   // B1: red[par] ready
        const float mb0 = fmaxf(fmaxf(red[par][0][ln], red[par][1][ln]),
                                fmaxf(red[par][2][ln], red[par][3][ln]));
        const float mb1 = fmaxf(fmaxf(red[par][0][32 + ln], red[par][1][32 + ln]),
                                fmaxf(red[par][2][32 + ln], red[par][3][32 + ln]));
        const float mnew0 = fmaxf(mold0, mb0);
        const float mnew1 = fmaxf(mold1, mb1);
        const float fs0 = __expf(mold0 - mnew0);
        const float fs1 = __expf(mold1 - mnew1);
        mold0 = mnew0; mold1 = mnew1;
        rs0 *= fs0; rs1 *= fs1;
#pragma unroll
        for (int r = 0; r < 16; r++) { acc0[r] *= fs0; acc1[r] *= fs1; }

        {
            float p[16];
#pragma unroll
            for (int r = 0; r < 16; r++) { p[r] = __expf(s0[r] - mnew0); rs0 += p[r]; }
            float xx[16];
#pragma unroll
            for (int r = 0; r < 16; r++) xx[r] = __shfl_xor(p[r], 32);
            unsigned short f0[8], f1[8];
#pragma unroll
            for (int i = 0; i < 4; i++) {
                f0[i]     = f2bf(g ? xx[4 + i]  : p[i]);
                f0[4 + i] = f2bf(g ? p[4 + i]   : xx[i]);
                f1[i]     = f2bf(g ? xx[12 + i] : p[8 + i]);
                f1[4 + i] = f2bf(g ? p[12 + i]  : xx[8 + i]);
            }
            *(short8*)(&Pf[par][((w << 2) + g) * 512 + (ln << 3)])     = *(short8*)f0;
            *(short8*)(&Pf[par][((w << 2) + 2 + g) * 512 + (ln << 3)]) = *(short8*)f1;
        }
        {
            float p[16];
#pragma unroll
            for (int r = 0; r < 16; r++) { p[r] = __expf(s1[r] - mnew1); rs1 += p[r]; }
            float xx[16];
#pragma unroll
            for (int r = 0; r < 16; r++) xx[r] = __shfl_xor(p[r], 32);
            unsigned short f0[8], f1[8];
#pragma unroll
            for (int i = 0; i < 4; i++) {
                f0[i]     = f2bf(g ? xx[4 + i]  : p[i]);
                f0[4 + i] = f2bf(g ? p[4 + i]   : xx[i]);
                f1[i]     = f2bf(g ? xx[12 + i] : p[8 + i]);
                f1[4 + i] = f2bf(g ? p[12 + i]  : xx[8 + i]);
            }
            *(short8*)(&Pf[par][((w << 2) + g) * 512 + 256 + (ln << 3)])     = *(short8*)f0;
            *(short8*)(&Pf[par][((w << 2) + 2 + g) * 512 + 256 + (ln << 3)]) = *(short8*)f1;
        }
        __syncthreads();                                   // B2: Pf[par] ready

#pragma unroll
        for (int kk = 0; kk < 8; kk++) {
            short8 vfrag = *(const short8*)(vb + (((size_t)b * 128 + c0 + ln) << 12)
                                               + m0 + (kk << 4) + (g << 3));
            short8 pf0 = *(const short8*)(&Pf[par][((kk << 1) + g) * 512 + (ln << 3)]);
            short8 pf1 = *(const short8*)(&Pf[par][((kk << 1) + g) * 512 + 256 + (ln << 3)]);
            acc0 = __builtin_amdgcn_mfma_f32_32x32x16_bf16(vfrag, pf0, acc0, 0, 0, 0);
            acc1 = __builtin_amdgcn_mfma_f32_32x32x16_bf16(vfrag, pf1, acc1, 0, 0, 0);
        }
        par ^= 1;
    }

    rs0 += __shfl_xor(rs0, 32);
    rs1 += __shfl_xor(rs1, 32);
    if (L < 32) { redS[w][L] = rs0; redS[w][32 + L] = rs1; }
    __syncthreads();
    const float inv0 = 1.f / (redS[0][ln] + redS[1][ln] + redS[2][ln] + redS[3][ln]);
    const float inv1 = 1.f / (redS[0][32 + ln] + redS[1][32 + ln]
                            + redS[2][32 + ln] + redS[3][32 + ln]);
#pragma unroll
    for (int r = 0; r < 16; r++) {
        int c = c0 + (r & 3) + ((r >> 2) << 3) + (g << 2);
        size_t idx0 = (((size_t)b * 128 + c) << 12) + n0 + ln;
        outb[idx0]      = f2bf(fmaf(al, acc0[r] * inv0, Y[idx0]));
        outb[idx0 + 32] = f2bf(fmaf(al, acc1[r] * inv1, Y[idx0 + 32]));
    }
}

// ---- CAM feat: emits hi/lo bf16 directly (feeds conv2c) -------------------
__global__ __launch_bounds__(256) void cam_feat(
    const float* __restrict__ attn, const float* __restrict__ Bf,
    const float* __restrict__ beta, unsigned short* __restrict__ oh,
    unsigned short* __restrict__ ol)
{
    const int t  = threadIdx.x;
    const int n  = (blockIdx.x << 8) + t;
    const int c0 = blockIdx.y << 5;
    const int b  = blockIdx.z;
    __shared__ float al[32 * 128];
    for (int idx = t; idx < 4096; idx += 256)
        al[idx] = attn[(size_t)b * 16384 + (c0 + (idx >> 7)) * 128 + (idx & 127)];
    __syncthreads();
    float acc[32];
#pragma unroll
    for (int k = 0; k < 32; k++) acc[k] = 0.f;
    for (int d = 0; d < 128; ++d) {
        float v = Bf[(((size_t)b * 128 + d) << 12) + n];
#pragma unroll
        for (int k = 0; k < 32; k++) acc[k] = fmaf(al[k * 128 + d], v, acc[k]);
    }
    float be = beta[0];
#pragma unroll
    for (int k = 0; k < 32; k++) {
        size_t idx = (((size_t)b * 128 + c0 + k) << 12) + n;
        float v = fmaf(be, acc[k], Bf[idx]);
        unsigned short hi = f2bf(v);
        oh[idx] = hi;
        ol[idx] = f2bf(v - bf2f(hi));
    }
}

// ---- Final heads ----
__global__ __launch_bounds__(256) void heads(
    const float* __restrict__ FP, const float* __restrict__ FC,
    const float* __restrict__ Wout, const float* __restrict__ bout,
    const float* __restrict__ Wp3, const float* __restrict__ bp3,
    const float* __restrict__ Wc3, const float* __restrict__ bc3,
    float* __restrict__ out)
{
    const int t = threadIdx.x;
    const int n = (blockIdx.x << 8) + t;
    const int b = blockIdx.y;
    __shared__ float wl[3 * 19 * 128];
    __shared__ float bl[3 * 19];
    for (int idx = t; idx < 2432; idx += 256) {
        wl[idx]        = Wout[idx];
        wl[2432 + idx] = Wp3[idx];
        wl[4864 + idx] = Wc3[idx];
    }
    if (t < 19) { bl[t] = bout[t]; bl[19 + t] = bp3[t]; bl[38 + t] = bc3[t]; }
    __syncthreads();
    float am[19], ap[19], ac[19];
#pragma unroll
    for (int o = 0; o < 19; o++) { am[o] = 0.f; ap[o] = 0.f; ac[o] = 0.f; }
    for (int chn = 0; chn < 128; ++chn) {
        float pv = FP[(((size_t)b * 128 + chn) << 12) + n];
        float cv = FC[(((size_t)b * 128 + chn) << 12) + n];
        float fv = pv + cv;
#pragma unroll
        for (int o = 0; o < 19; o++) {
            am[o] = fmaf(wl[o * 128 + chn], fv, am[o]);
            ap[o] = fmaf(wl[2432 + o * 128 + chn], pv, ap[o]);
            ac[o] = fmaf(wl[4864 + o * 128 + chn], cv, ac[o]);
        }
    }
    const size_t OS = (size_t)8 * 19 * 4096;
#pragma unroll
    for (int o = 0; o < 19; o++) {
        size_t base = (((size_t)b * 19 + o) << 12) + n;
        out[base]          = 1.f / (1.f + __expf(-(am[o] + bl[o])));
        out[OS + base]     = 1.f / (1.f + __expf(-(ap[o] + bl[19 + o])));
        out[2 * OS + base] = 1.f / (1.f + __expf(-(ac[o] + bl[38 + o])));
    }
}

extern "C" void kernel_launch(void* const* d_in, const int* in_sizes, int n_in,
                              void* d_out, int out_size, void* d_ws, size_t ws_size,
                              hipStream_t stream)
{
    const float* x     = (const float*)d_in[0];
    const float* Wp1   = (const float*)d_in[1];
    const float* bnp1  = (const float*)d_in[2];
    const float* Wc1   = (const float*)d_in[3];
    const float* bnc1  = (const float*)d_in[4];
    const float* Wb    = (const float*)d_in[5];
    const float* bb    = (const float*)d_in[6];
    const float* Wc    = (const float*)d_in[7];
    const float* bcv   = (const float*)d_in[8];
    const float* Wd    = (const float*)d_in[9];
    const float* bd    = (const float*)d_in[10];
    const float* alpha = (const float*)d_in[11];
    const float* beta  = (const float*)d_in[12];
    const float* Wp2   = (const float*)d_in[13];
    const float* bnp2  = (const float*)d_in[14];
    const float* Wc2   = (const float*)d_in[15];
    const float* bnc2  = (const float*)d_in[16];
    const float* Wout  = (const float*)d_in[17];
    const float* bo    = (const float*)d_in[18];
    const float* Wp3   = (const float*)d_in[19];
    const float* bp3   = (const float*)d_in[20];
    const float* Wc3   = (const float*)d_in[21];
    const float* bc3   = (const float*)d_in[22];
    float* out = (float*)d_out;

    char* ws = (char*)d_ws;
    const size_t MB = 1u << 20;
    const size_t W1SZ = (size_t)32 * 18432 * 2;
    const size_t W2SZ = (size_t)8 * 18432 * 2;
    float*          bufA     = (float*)(ws);
    float*          bufB     = (float*)(ws + 16 * MB);
    unsigned short* vb       = (unsigned short*)(ws + 32 * MB);  // 8MB
    float*          egy_part = (float*)(ws + 40 * MB);           // 4MB
    float*          bufD     = (float*)(ws + 32 * MB);           // conv2p out (later)
    unsigned short* bh       = (unsigned short*)(ws + 48 * MB);  // 8MB
    unsigned short* blo      = (unsigned short*)(ws + 56 * MB);  // 8MB
    unsigned short* pam_bf   = (unsigned short*)(ws + 48 * MB);  // after Gram
    unsigned short* c2h      = (unsigned short*)(ws + 48 * MB);  // after conv2p
    unsigned short* c2l      = (unsigned short*)(ws + 56 * MB);
    unsigned short* qt       = (unsigned short*)(ws + 64 * MB);
    unsigned short* kt       = (unsigned short*)(ws + 65 * MB);
    float*          egy      = (float*)(ws + 66 * MB + (1u << 17));
    unsigned short* wp1      = (unsigned short*)(ws + 67 * MB);
    unsigned short* wc1h     = (unsigned short*)(ws + 67 * MB + W1SZ);
    unsigned short* wc1l     = (unsigned short*)(ws + 67 * MB + 2 * W1SZ);
    unsigned short* wp2      = (unsigned short*)(ws + 67 * MB + 3 * W1SZ);
    unsigned short* wc2h     = (unsigned short*)(ws + 67 * MB + 3 * W1SZ + W2SZ);
    unsigned short* wc2l     = (unsigned short*)(ws + 67 * MB + 3 * W1SZ + 2 * W2SZ);

    dim3 blk(256);
    const int n1 = 32 * 18432;
    const int n2 = 8 * 18432;
    wpack_kernel<<<dim3((n1 + 255) / 256), blk, 0, stream>>>(Wp1, wp1, 512, n1);
    wpack_kernel<<<dim3((n2 + 255) / 256), blk, 0, stream>>>(Wp2, wp2, 128, n2);
    wpack_split_kernel<<<dim3((n1 + 255) / 256), blk, 0, stream>>>(Wc1, wc1h, wc1l, 512, n1);
    wpack_split_kernel<<<dim3((n2 + 255) / 256), blk, 0, stream>>>(Wc2, wc2h, wc2l, 128, n2);

    // fused conv1p + conv1c (64px waves, W-reuse x2)
    conv3x3_merged<<<dim3(64, 1, 8), blk, 0, stream>>>(x, wp1, wc1h, wc1l, bnp1, bnc1,
                                                       bufA, bufB, bh, blo);
    // CAM Gram (triangle) + softmax
    cam_energy_mfma<<<dim3(10, 8, 8), blk, 0, stream>>>(bh, blo, egy_part);
    cam_softmax_fused<<<dim3(8, 8), blk, 0, stream>>>(egy_part, egy);
    // PAM
    pam_qk_1x1<<<dim3(16, 8), blk, 0, stream>>>(bufA, Wb, bb, Wc, bcv, qt, kt);
    pam_v_1x1<<<dim3(16, 4, 8), blk, 0, stream>>>(bufA, Wd, bd, vb);
    pam_attn_mfma<<<dim3(64, 8), blk, 0, stream>>>(qt, kt, vb, alpha, bufA, pam_bf);
    // conv2p (reads pam_bf, writes bufD over vb/egy_part which are now dead)
    conv3x3_bf<<<dim3(64, 1, 8), blk, 0, stream>>>(pam_bf, 128, wp2, bnp2, bufD);
    // CAM tail (c2h/c2l overwrite pam_bf region after conv2p consumed it)
    cam_feat<<<dim3(16, 4, 8), blk, 0, stream>>>(egy, bufB, beta, c2h, c2l);
    conv3x3_hilo_bf<<<dim3(64, 1, 8), blk, 0, stream>>>(c2h, c2l, 128, wc2h, wc2l, bnc2, bufA);
    // fusion + heads
    heads<<<dim3(16, 8), blk, 0, stream>>>(bufD, bufA, Wout, bo, Wp3, bp3, Wc3, bc3, out);
}